// Round 1
// baseline (98.255 us; speedup 1.0000x reference)
//
#include <hip/hip_runtime.h>

#define IN_F 512
#define OUT_F 64
#define MCOLS 1024            // OUT_F * INTER
#define OUT_STRIDE 576        // IN_F + OUT_F

// ---------------- Kernel A: M = x @ T  (+ x passthrough copy, + o_b init to -1) ----
// Tile: 32 rows x 64 cols, 256 threads (16x16), micro-tile 2x4, K staged in 32-chunks.
__global__ __launch_bounds__(256) void gemm_init_kernel(
    const float* __restrict__ x, const float* __restrict__ T,
    float* __restrict__ M, float* __restrict__ out)
{
    __shared__ float xs[32][33];   // [kk][ii], +1 pad to break write conflicts
    __shared__ float ts[32][64];   // [kk][jj]

    const int tid = threadIdx.x;
    const int tx = tid & 15;       // col quad index (4 cols each)
    const int ty = tid >> 4;       // row pair index (2 rows each)
    const int c0 = blockIdx.x * 64;
    const int r0 = blockIdx.y * 32;

    float acc[2][4] = {{0.f,0.f,0.f,0.f},{0.f,0.f,0.f,0.f}};

    for (int kc = 0; kc < IN_F; kc += 32) {
        // stage x tile: 32 rows x 32 k -> xs[kk][ii]
        {
            const int ii = tid >> 3;        // 0..31
            const int kq = tid & 7;         // 0..7
            const float4 v = *(const float4*)(x + (r0 + ii) * IN_F + kc + kq * 4);
            xs[kq*4+0][ii] = v.x;
            xs[kq*4+1][ii] = v.y;
            xs[kq*4+2][ii] = v.z;
            xs[kq*4+3][ii] = v.w;
        }
        // stage T tile: 32 k x 64 cols -> ts[kk][jj]
        {
            const int jq = tid & 15;
#pragma unroll
            for (int h = 0; h < 2; ++h) {
                const int kk = (tid >> 4) + h * 16;
                const float4 v = *(const float4*)(T + (size_t)(kc + kk) * MCOLS + c0 + jq * 4);
                *(float4*)&ts[kk][jq * 4] = v;
            }
        }
        __syncthreads();
#pragma unroll
        for (int kk = 0; kk < 32; ++kk) {
            const float a0 = xs[kk][ty*2 + 0];
            const float a1 = xs[kk][ty*2 + 1];
            const float4 b = *(const float4*)&ts[kk][tx * 4];
            acc[0][0] += a0 * b.x; acc[0][1] += a0 * b.y;
            acc[0][2] += a0 * b.z; acc[0][3] += a0 * b.w;
            acc[1][0] += a1 * b.x; acc[1][1] += a1 * b.y;
            acc[1][2] += a1 * b.z; acc[1][3] += a1 * b.w;
        }
        __syncthreads();
    }

#pragma unroll
    for (int u = 0; u < 2; ++u) {
        const float4 w = make_float4(acc[u][0], acc[u][1], acc[u][2], acc[u][3]);
        *(float4*)(M + (size_t)(r0 + ty*2 + u) * MCOLS + c0 + tx * 4) = w;
    }

    // ---- epilogue: copy x into out (exact fp32 passthrough) ----
    const int bid = blockIdx.y * 16 + blockIdx.x;   // 0..255
    {
        const int idx = (bid * 256 + tid) * 4;      // float index into x (0..262143)
        const int i = idx >> 9;                     // /512
        const int c = idx & 511;
        *(float4*)(out + (size_t)i * OUT_STRIDE + c) = *(const float4*)(x + idx);
    }
    // ---- init o_b region to -1 (cancels the self-pair exp(0)=1 term) ----
    if (tid < 128) {
        const int idx = bid * 128 + tid;            // 0..32767
        const int i = idx >> 6;
        const int o = idx & 63;
        out[(size_t)i * OUT_STRIDE + IN_F + o] = -1.0f;
    }
}

// ---------------- Kernel B: pairwise L1 -> exp -> sum ------------------------------
// 512 blocks = 32 i-tiles (16 rows each) x 16 j-chunks (32 j each), 256 threads.
// Thread owns (4 i-rows, 1 o-col): 64 M-floats in registers. j-rows staged 8 at a
// time into LDS in [k][o] layout (lane o -> bank o%32, 2-way = free).
__global__ __launch_bounds__(256) void pairwise_kernel(
    const float* __restrict__ M, float* __restrict__ out)
{
    __shared__ float sj[8 * 1024];   // 32 KB

    const int tid = threadIdx.x;
    const int o  = tid & 63;
    const int ig = tid >> 6;             // 0..3
    const int it = blockIdx.x & 31;
    const int jc = blockIdx.x >> 5;
    const int i0 = it * 16;
    const int j0 = jc * 32;

    // register fragments: M[i0+ig*4+r][o*16 + k]
    float mi[4][16];
#pragma unroll
    for (int r = 0; r < 4; ++r) {
        const float* rowp = M + (size_t)(i0 + ig*4 + r) * MCOLS + o * 16;
#pragma unroll
        for (int q = 0; q < 4; ++q) {
            const float4 v = *(const float4*)(rowp + q * 4);
            mi[r][q*4+0] = v.x; mi[r][q*4+1] = v.y;
            mi[r][q*4+2] = v.z; mi[r][q*4+3] = v.w;
        }
    }

    float acc[4] = {0.f, 0.f, 0.f, 0.f};

    const int ko = 4 * (tid & 3);   // k base of this thread's staged float4
    const int oo = tid >> 2;        // o of this thread's staged float4

    for (int jb = 0; jb < 32; jb += 8) {
        // stage 8 j-rows, transposed to [k][o]
#pragma unroll
        for (int q = 0; q < 8; ++q) {
            const float4 v = *(const float4*)(M + (size_t)(j0 + jb + q) * MCOLS + tid * 4);
            float* s = sj + q * 1024 + oo;
            s[(ko+0)*64] = v.x;
            s[(ko+1)*64] = v.y;
            s[(ko+2)*64] = v.z;
            s[(ko+3)*64] = v.w;
        }
        __syncthreads();
#pragma unroll
        for (int q = 0; q < 8; ++q) {
            const float* s = sj + q * 1024 + o;
            float vj[16];
#pragma unroll
            for (int k = 0; k < 16; ++k) vj[k] = s[k * 64];
#pragma unroll
            for (int r = 0; r < 4; ++r) {
                float l1 = 0.f;
#pragma unroll
                for (int k = 0; k < 16; ++k) l1 += fabsf(mi[r][k] - vj[k]);
                acc[r] += __expf(-l1);
            }
        }
        __syncthreads();
    }

#pragma unroll
    for (int r = 0; r < 4; ++r) {
        atomicAdd(out + (size_t)(i0 + ig*4 + r) * OUT_STRIDE + IN_F + o, acc[r]);
    }
}

extern "C" void kernel_launch(void* const* d_in, const int* in_sizes, int n_in,
                              void* d_out, int out_size, void* d_ws, size_t ws_size,
                              hipStream_t stream) {
    const float* x = (const float*)d_in[0];
    const float* T = (const float*)d_in[1];
    float* out = (float*)d_out;
    float* M = (float*)d_ws;     // 512*1024 fp32 = 2 MB scratch

    dim3 gridA(16, 16);          // 1024-col tiles of 64 x 512-row tiles of 32
    gemm_init_kernel<<<gridA, 256, 0, stream>>>(x, T, M, out);
    pairwise_kernel<<<512, 256, 0, stream>>>(M, out);
}

// Round 2
// 83.863 us; speedup vs baseline: 1.1716x; 1.1716x over previous
//
#include <hip/hip_runtime.h>

#define OUT_STRIDE 576   // IN_F(512) + OUT_F(64)

typedef __attribute__((ext_vector_type(8))) short bf16x8;
typedef __attribute__((ext_vector_type(4))) float f32x4;

__device__ inline unsigned short f2bf(float f) {
    unsigned u = __float_as_uint(f);
    u = (u + 0x7FFFu + ((u >> 16) & 1u)) >> 16;   // RNE
    return (unsigned short)u;
}

// ---------------- Kernel P: transpose+convert T [512 k][1024 n] fp32 -> Tb [1024 n][512 k] bf16
__global__ __launch_bounds__(256) void transpose_T_kernel(
    const float* __restrict__ T, unsigned short* __restrict__ Tb)
{
    __shared__ float tt[64][68];   // 64x64 tile, pad to 68 (16B-aligned float4 rows)
    const int b = blockIdx.x;      // 128 blocks: 8 k-tiles x 16 n-tiles
    const int t = threadIdx.x;
    const int k0 = (b & 7) * 64, n0 = (b >> 3) * 64;
    // read: 4 passes of (16 k-rows x 64 n) via float4 along n
    const int n4 = (t & 15) * 4, kr = t >> 4;
#pragma unroll
    for (int rr = 0; rr < 4; ++rr) {
        const int k = rr * 16 + kr;
        *(float4*)&tt[k][n4] = *(const float4*)(T + (size_t)(k0 + k) * 1024 + n0 + n4);
    }
    __syncthreads();
    // write: Tb[n][k] as ushort4 (4 bf16)
#pragma unroll
    for (int q = 0; q < 4; ++q) {
        const int g = q * 256 + t;
        const int nn = g >> 4, c = g & 15;
        ushort4 w;
        w.x = f2bf(tt[c * 4 + 0][nn]);
        w.y = f2bf(tt[c * 4 + 1][nn]);
        w.z = f2bf(tt[c * 4 + 2][nn]);
        w.w = f2bf(tt[c * 4 + 3][nn]);
        *(ushort4*)(Tb + (size_t)(n0 + nn) * 512 + k0 + c * 4) = w;
    }
}

// ---------------- Kernel G: M = x @ T via bf16 MFMA 16x16x32; + out init epilogue ----
// Tile 32 rows x 64 cols, 256 thr = 4 waves, wave w: rows (w>>1)*16, cols (w&1)*32 (2 n-tiles).
__global__ __launch_bounds__(256) void gemm_kernel(
    const float* __restrict__ x, const unsigned short* __restrict__ Tb,
    float* __restrict__ M, float* __restrict__ out)
{
    __shared__ unsigned short As[32 * 72];   // [m][k] pad 72 (144B rows: 16B-aligned)
    __shared__ unsigned short Bs[64 * 72];   // [n][k] pad 72
    const int t = threadIdx.x;
    const int bx = blockIdx.x & 15, by = blockIdx.x >> 4;
    const int c0 = bx * 64, r0 = by * 32;
    const int lane = t & 63, w = t >> 6;
    const int m0 = (w >> 1) * 16, nb = (w & 1) * 32;
    const int fl = lane & 15, q8 = (lane >> 4) * 8;
    const int arow = t >> 3, k8 = (t & 7) * 8;

    f32x4 acc0 = {0.f, 0.f, 0.f, 0.f}, acc1 = {0.f, 0.f, 0.f, 0.f};

    for (int kc = 0; kc < 512; kc += 64) {
        // stage A: 32 rows x 64 k, fp32 -> bf16 on the fly
        {
            const float4 u = *(const float4*)(x + (size_t)(r0 + arow) * 512 + kc + k8);
            const float4 v = *(const float4*)(x + (size_t)(r0 + arow) * 512 + kc + k8 + 4);
            ushort4 w0, w1;
            w0.x = f2bf(u.x); w0.y = f2bf(u.y); w0.z = f2bf(u.z); w0.w = f2bf(u.w);
            w1.x = f2bf(v.x); w1.y = f2bf(v.y); w1.z = f2bf(v.z); w1.w = f2bf(v.w);
            *(ushort4*)&As[arow * 72 + k8] = w0;
            *(ushort4*)&As[arow * 72 + k8 + 4] = w1;
        }
        // stage B: 64 n x 64 k (already bf16, [n][k]) — pure 16B copies
#pragma unroll
        for (int h = 0; h < 2; ++h) {
            const int n = arow + h * 32;
            *(uint4*)&Bs[n * 72 + k8] =
                *(const uint4*)(Tb + (size_t)(c0 + n) * 512 + kc + k8);
        }
        __syncthreads();
        // fragments: A[m=lane&15][k=(lane>>4)*8+j]; B[n=lane&15][k=(lane>>4)*8+j]
        const bf16x8 a0  = *(const bf16x8*)&As[(m0 + fl) * 72 + q8];
        const bf16x8 a1  = *(const bf16x8*)&As[(m0 + fl) * 72 + 32 + q8];
        const bf16x8 b00 = *(const bf16x8*)&Bs[(nb + fl) * 72 + q8];
        const bf16x8 b01 = *(const bf16x8*)&Bs[(nb + fl) * 72 + 32 + q8];
        const bf16x8 b10 = *(const bf16x8*)&Bs[(nb + 16 + fl) * 72 + q8];
        const bf16x8 b11 = *(const bf16x8*)&Bs[(nb + 16 + fl) * 72 + 32 + q8];
        acc0 = __builtin_amdgcn_mfma_f32_16x16x32_bf16(a0, b00, acc0, 0, 0, 0);
        acc0 = __builtin_amdgcn_mfma_f32_16x16x32_bf16(a1, b01, acc0, 0, 0, 0);
        acc1 = __builtin_amdgcn_mfma_f32_16x16x32_bf16(a0, b10, acc1, 0, 0, 0);
        acc1 = __builtin_amdgcn_mfma_f32_16x16x32_bf16(a1, b11, acc1, 0, 0, 0);
        __syncthreads();
    }
    // C/D layout: col = lane&15, row = (lane>>4)*4 + reg
    const int orow = r0 + m0 + (lane >> 4) * 4;
#pragma unroll
    for (int r = 0; r < 4; ++r) {
        M[(size_t)(orow + r) * 1024 + c0 + nb + fl]      = acc0[r];
        M[(size_t)(orow + r) * 1024 + c0 + nb + 16 + fl] = acc1[r];
    }

    // ---- epilogue: copy x into out (exact fp32 passthrough) ----
    const int bid = blockIdx.x;    // 0..255
    {
        const int idx = (bid * 256 + t) * 4;
        const int i = idx >> 9, c = idx & 511;
        *(float4*)(out + (size_t)i * OUT_STRIDE + c) = *(const float4*)(x + idx);
    }
    // ---- init o_b region to -1 (cancels self-pair exp(0)=1) ----
    if (t < 128) {
        const int idx = bid * 128 + t;
        const int i = idx >> 6, o = idx & 63;
        out[(size_t)i * OUT_STRIDE + 512 + o] = -1.0f;
    }
}

// ---------------- Kernel B: pairwise L1 -> exp -> sum ------------------------------
// 1024 blocks = 32 i-tiles (16 rows) x 32 j-chunks (16 rows). Thread = (4 i-rows, 1 o).
// j-rows staged 8 at a time in LDS with 20-dword pad stride per o (uniform 8/bank),
// read back as 4x ds_read_b128.
__global__ __launch_bounds__(256, 4) void pairwise_kernel(
    const float* __restrict__ M, float* __restrict__ out)
{
    __shared__ float sj[8 * 1280];   // 40 KB -> 4 blocks/CU
    const int t = threadIdx.x;
    const int o = t & 63, ig = t >> 6;
    const int it = blockIdx.x & 31, jc = blockIdx.x >> 5;
    const int i0 = it * 16, j0 = jc * 16;

    float mi[4][16];
#pragma unroll
    for (int r = 0; r < 4; ++r) {
        const float* rp = M + (size_t)(i0 + ig * 4 + r) * 1024 + o * 16;
#pragma unroll
        for (int q = 0; q < 4; ++q) {
            const float4 v = *(const float4*)(rp + q * 4);
            mi[r][q * 4 + 0] = v.x; mi[r][q * 4 + 1] = v.y;
            mi[r][q * 4 + 2] = v.z; mi[r][q * 4 + 3] = v.w;
        }
    }
    float acc[4] = {0.f, 0.f, 0.f, 0.f};

    const int os = t >> 2, k4 = t & 3;
#pragma unroll
    for (int jb = 0; jb < 16; jb += 8) {
        // stage 8 j-rows: row q, thread t covers float4 #t of the row
#pragma unroll
        for (int q = 0; q < 8; ++q) {
            const float4 v = *(const float4*)(M + (size_t)(j0 + jb + q) * 1024 + t * 4);
            *(float4*)&sj[q * 1280 + os * 20 + k4 * 4] = v;
        }
        __syncthreads();
#pragma unroll
        for (int q = 0; q < 8; ++q) {
            const float* s = sj + q * 1280 + o * 20;
            float l1[4] = {0.f, 0.f, 0.f, 0.f};
#pragma unroll
            for (int q4 = 0; q4 < 4; ++q4) {
                const float4 v = *(const float4*)(s + q4 * 4);
#pragma unroll
                for (int r = 0; r < 4; ++r) {
                    l1[r] += fabsf(mi[r][q4 * 4 + 0] - v.x);
                    l1[r] += fabsf(mi[r][q4 * 4 + 1] - v.y);
                    l1[r] += fabsf(mi[r][q4 * 4 + 2] - v.z);
                    l1[r] += fabsf(mi[r][q4 * 4 + 3] - v.w);
                }
            }
#pragma unroll
            for (int r = 0; r < 4; ++r) acc[r] += __expf(-l1[r]);
        }
        __syncthreads();
    }
#pragma unroll
    for (int r = 0; r < 4; ++r)
        atomicAdd(out + (size_t)(i0 + ig * 4 + r) * OUT_STRIDE + 512 + o, acc[r]);
}

extern "C" void kernel_launch(void* const* d_in, const int* in_sizes, int n_in,
                              void* d_out, int out_size, void* d_ws, size_t ws_size,
                              hipStream_t stream) {
    const float* x = (const float*)d_in[0];
    const float* T = (const float*)d_in[1];
    float* out = (float*)d_out;
    float* M = (float*)d_ws;                                          // 2 MB fp32
    unsigned short* Tb = (unsigned short*)((char*)d_ws + (2 << 20));  // 1 MB bf16

    transpose_T_kernel<<<128, 256, 0, stream>>>(T, Tb);
    gemm_kernel<<<256, 256, 0, stream>>>(x, Tb, M, out);
    pairwise_kernel<<<1024, 256, 0, stream>>>(M, out);
}